// Round 8
// baseline (3226.463 us; speedup 1.0000x reference)
//
#include <hip/hip_runtime.h>

// TerminalGRU: B=256 T=256 D=512 H=1024 C=128
// Chunked pipeline (TC=32 steps x 8 chunks):
//   per chunk: k_cvtx -> k_gates (MFMA GEMM) -> k_scan (ring h, epoch-notify)
//              -> k_logits
// Round-7 post-mortem: 268us/chunk scan, ~7us/step pure wait. The 64-block
// shared-counter RMW at the MALL serializes (64 RMWs + 64 spin-waves on one
// line). This round: contention-free handshake --
//   producer: h-ring agent store -> vmcnt(0) -> barrier -> plain agent store
//             of epoch t+1 into its OWN notify word (no RMW)
//   consumer: wave0 polls all 64 words in ONE wave-wide coalesced load,
//             exits on __all(v >= t)
// Plus: hprev carried in registers (own slice), hsc store moved after notify.

#define DEVI __device__ __forceinline__

typedef __bf16 bf16x8 __attribute__((ext_vector_type(8)));
typedef float f32x4 __attribute__((ext_vector_type(4)));
typedef unsigned long long u64;

static constexpr int Bb = 256, Tt = 256, Dd = 512, Hh = 1024, Cc = 128;
static constexpr int G3 = 3072, DC = 640, TC = 32, NC = Tt / TC;
static constexpr int SLOTS = TC + 1;  // 33-slot h ring

DEVI unsigned short f2b(float f) {
  union { float f; unsigned u; } v; v.f = f;
  unsigned r = v.u + 0x7FFFu + ((v.u >> 16) & 1u);
  return (unsigned short)(r >> 16);
}
DEVI float b2f(unsigned short h) {
  union { unsigned u; float f; } v; v.u = ((unsigned)h) << 16; return v.f;
}

// ---------------- prep kernels ----------------

__global__ __launch_bounds__(256) void k_cvt(const float* __restrict__ x,
                                             unsigned short* __restrict__ o, int n) {
  int i = (blockIdx.x * 256 + threadIdx.x) * 8;
  if (i >= n) return;
  float4 a = *(const float4*)(x + i), b = *(const float4*)(x + i + 4);
  uint4 u;
  u.x = (unsigned)f2b(a.x) | ((unsigned)f2b(a.y) << 16);
  u.y = (unsigned)f2b(a.z) | ((unsigned)f2b(a.w) << 16);
  u.z = (unsigned)f2b(b.x) | ((unsigned)f2b(b.y) << 16);
  u.w = (unsigned)f2b(b.z) | ((unsigned)f2b(b.w) << 16);
  *(uint4*)(o + i) = u;
}

__global__ __launch_bounds__(256) void k_cvt_wa(const float* __restrict__ Wih,
                                                unsigned short* __restrict__ Wa) {
  int u = blockIdx.x * 256 + threadIdx.x;
  int g = u >> 6, d = (u & 63) * 8;
  const float* p = Wih + (size_t)g * DC + d;
  float4 a = *(const float4*)p, b = *(const float4*)(p + 4);
  uint4 o;
  o.x = (unsigned)f2b(a.x) | ((unsigned)f2b(a.y) << 16);
  o.y = (unsigned)f2b(a.z) | ((unsigned)f2b(a.w) << 16);
  o.z = (unsigned)f2b(b.x) | ((unsigned)f2b(b.y) << 16);
  o.w = (unsigned)f2b(b.z) | ((unsigned)f2b(b.w) << 16);
  *(uint4*)(Wa + (size_t)g * Dd + d) = o;
}

__global__ __launch_bounds__(256) void k_cvt_wct(const float* __restrict__ Wih,
                                                 unsigned short* __restrict__ WcT) {
  int g = blockIdx.x * 256 + threadIdx.x;
  int c = blockIdx.y;
  WcT[(size_t)c * G3 + g] = f2b(Wih[(size_t)g * DC + Dd + c]);
}

__global__ __launch_bounds__(256) void k_pid(const float* __restrict__ ts,
                                             int* __restrict__ pid) {
  int bt = blockIdx.x * 256 + threadIdx.x;
  int t = bt & (Tt - 1);
  if (t == 0) { pid[bt] = -1; return; }
  const float* p = ts + (size_t)(bt - 1) * Cc;
  int id = 0;
  for (int c = 0; c < Cc; c += 4) {
    float4 v = *(const float4*)(p + c);
    if (v.x > 0.5f) id = c;
    if (v.y > 0.5f) id = c + 1;
    if (v.z > 0.5f) id = c + 2;
    if (v.w > 0.5f) id = c + 3;
  }
  pid[bt] = id;
}

__global__ __launch_bounds__(256) void k_cvtx(const float* __restrict__ gru,
                                              unsigned short* __restrict__ Xc, int t0) {
  int u = (blockIdx.x * 256 + threadIdx.x) * 8;
  int m = u >> 9, d = u & 511;
  int b = m >> 5, tl = m & 31;
  const float* p = gru + ((size_t)(b * Tt + t0 + tl)) * Dd + d;
  float4 a = *(const float4*)p, c = *(const float4*)(p + 4);
  uint4 o;
  o.x = (unsigned)f2b(a.x) | ((unsigned)f2b(a.y) << 16);
  o.y = (unsigned)f2b(a.z) | ((unsigned)f2b(a.w) << 16);
  o.z = (unsigned)f2b(c.x) | ((unsigned)f2b(c.y) << 16);
  o.w = (unsigned)f2b(c.z) | ((unsigned)f2b(c.w) << 16);
  *(uint4*)(Xc + (size_t)m * Dd + d) = o;
}

// ---------------- gates GEMM (per chunk, M=8192) ----------------
__global__ __launch_bounds__(256) void k_gates(const unsigned short* __restrict__ Xc,
                                               const unsigned short* __restrict__ Wa,
                                               const unsigned short* __restrict__ WcT,
                                               const float* __restrict__ bih,
                                               const int* __restrict__ pid,
                                               unsigned short* __restrict__ gx, int t0) {
  int m0 = blockIdx.x * 128, n0 = blockIdx.y * 128;
  int l = threadIdx.x & 63, w = threadIdx.x >> 6;
  int wm = w >> 1, wn = w & 1;
  int r0 = m0 + 64 * wm, c0 = n0 + 64 * wn;
  int lr = l & 15, lk = (l >> 4) * 8;
  f32x4 acc[4][4] = {};
  for (int kk = 0; kk < 16; ++kk) {
    int k = kk * 32 + lk;
    bf16x8 a[4], b[4];
#pragma unroll
    for (int mf = 0; mf < 4; ++mf)
      a[mf] = *(const bf16x8*)(Xc + (size_t)(r0 + 16 * mf + lr) * Dd + k);
#pragma unroll
    for (int nf = 0; nf < 4; ++nf)
      b[nf] = *(const bf16x8*)(Wa + (size_t)(c0 + 16 * nf + lr) * Dd + k);
#pragma unroll
    for (int mf = 0; mf < 4; ++mf)
#pragma unroll
      for (int nf = 0; nf < 4; ++nf)
        acc[mf][nf] = __builtin_amdgcn_mfma_f32_16x16x32_bf16(a[mf], b[nf], acc[mf][nf], 0, 0, 0);
  }
  int ri = (l >> 4) * 4;
  for (int mf = 0; mf < 4; ++mf) {
    int rowb = r0 + 16 * mf + ri;
    int pd[4];
#pragma unroll
    for (int i = 0; i < 4; ++i) {
      int rr = rowb + i;
      pd[i] = pid[(size_t)(rr >> 5) * Tt + t0 + (rr & 31)];
    }
    for (int nf = 0; nf < 4; ++nf) {
      int g = c0 + 16 * nf + lr;
      float bi = bih[g];
#pragma unroll
      for (int i = 0; i < 4; ++i) {
        float v = acc[mf][nf][i] + bi;
        if (pd[i] >= 0) v += b2f(WcT[(size_t)pd[i] * G3 + g]);
        gx[(size_t)(rowb + i) * G3 + g] = f2b(v);
      }
    }
  }
}

// ---------------- recurrent scan chunk (ring h, epoch notify) ----------------
// 256 blocks x 256 threads. xcd=bid&7, slot=bid>>3, mg=xcd>>1 (rows [64mg,+64)),
// nb=slot*2+(xcd&1) (hcols [16nb,+16)). Wave w: K-slice [256w,+256).
// notify[mg][64]: per-block epoch words (monotone); consumer polls via one
// wave-wide gather.
__global__ __launch_bounds__(256, 1) void k_scan(const unsigned short* __restrict__ Whh,
                                                 const float* __restrict__ bhh,
                                                 const unsigned short* __restrict__ gx,
                                                 unsigned short* __restrict__ hring,
                                                 unsigned short* __restrict__ hsc,
                                                 unsigned int* __restrict__ notify,
                                                 int t0) {
  __shared__ float red[4 * 64 * 52];  // [wave][row64][3*16 pad52] = 53.2KB
  const int tid = threadIdx.x;
  const int l = tid & 63, w = tid >> 6;
  const int bid = blockIdx.x;
  const int xcd = bid & 7, slot = bid >> 3;
  const int mg = xcd >> 1, nb = slot * 2 + (xcd & 1);
  const int gidx = slot * 2 + (xcd & 1);  // block index within group [0,64)
  const int lr = l & 15, lk = (l >> 4) * 8;
  const int hcolBase = 16 * nb;
  const int ri = (l >> 4) * 4;

  // resident W_hh fragments: 3 gates x 8 k-steps (rows {hcol, H+hcol, 2H+hcol})
  bf16x8 Breg[3][8];
#pragma unroll
  for (int nf = 0; nf < 3; ++nf) {
    int wrow = nf * Hh + hcolBase + lr;
#pragma unroll
    for (int kk = 0; kk < 8; ++kk) {
      int k = 256 * w + 32 * kk + lk;
      Breg[nf][kk] = *(const bf16x8*)(Whh + (size_t)wrow * Hh + k);
    }
  }

  // epilogue mapping: thread -> 1 row x 4 cols (8-byte h I/O)
  const int erow = tid >> 2, ej0 = (tid & 3) * 4;
  const int eb = 64 * mg + erow;
  const int ecol = hcolBase + ej0;
  const float4 bhr4 = *(const float4*)(bhh + ecol);
  const float4 bhz4 = *(const float4*)(bhh + Hh + ecol);
  const float4 bhn4 = *(const float4*)(bhh + 2 * Hh + ecol);

  u64 hsave = 0;  // own h slice carried in registers across steps

  for (int tl = 0; tl < TC; ++tl) {
    const int t = t0 + tl;
    const unsigned short* hcur = hring + (size_t)(t % SLOTS) * (Bb * Hh);
    u64* hnq = (u64*)hring + (size_t)((t + 1) % SLOTS) * (Bb * Hh / 4);

    // prefetch gx for this step (produced by k_gates; safe pre-wait)
    const size_t gxo = (size_t)(eb * TC + tl) * G3;
    uint2 gr = *(const uint2*)(gx + gxo + ecol);
    uint2 gz = *(const uint2*)(gx + gxo + Hh + ecol);
    uint2 gn = *(const uint2*)(gx + gxo + 2 * Hh + ecol);

    // wait: all 64 blocks of this row-group have produced h[t]
    if (t > 0) {
      if (w == 0) {
        const unsigned int* np = notify + (mg << 6);
        for (;;) {
          unsigned int v = __hip_atomic_load(np + l, __ATOMIC_RELAXED,
                                             __HIP_MEMORY_SCOPE_AGENT);
          if (__all((int)(v >= (unsigned)t))) break;
          __builtin_amdgcn_s_sleep(4);
        }
      }
      __syncthreads();
    }
    asm volatile("" ::: "memory");

    // hprev: register-carried own slice (ring load only at chunk entry)
    u64 hprev = (tl == 0) ? *(const u64*)(hcur + (size_t)eb * Hh + ecol) : hsave;

    f32x4 acc[4][3] = {};
#pragma unroll
    for (int kk = 0; kk < 8; ++kk) {
      int k = 256 * w + 32 * kk + lk;
      bf16x8 a[4];
#pragma unroll
      for (int mf = 0; mf < 4; ++mf)
        a[mf] = *(const bf16x8*)(hcur + (size_t)(64 * mg + 16 * mf + lr) * Hh + k);
#pragma unroll
      for (int mf = 0; mf < 4; ++mf)
#pragma unroll
        for (int nf = 0; nf < 3; ++nf)
          acc[mf][nf] = __builtin_amdgcn_mfma_f32_16x16x32_bf16(a[mf], Breg[nf][kk], acc[mf][nf], 0, 0, 0);
    }

    // partials -> LDS (cols: gate*16 + lr)
#pragma unroll
    for (int mf = 0; mf < 4; ++mf)
#pragma unroll
      for (int nf = 0; nf < 3; ++nf)
#pragma unroll
        for (int i = 0; i < 4; ++i)
          red[(w * 64 + 16 * mf + ri + i) * 52 + 16 * nf + lr] = acc[mf][nf][i];
    __syncthreads();

    // reduce 4 wave-partials + gate math, 1 row x 4 cols per thread
    f32x4 vr = {}, vz = {}, vn = {};
#pragma unroll
    for (int w2 = 0; w2 < 4; ++w2) {
      const float* rp = &red[(w2 * 64 + erow) * 52];
      vr += *(const f32x4*)(rp + ej0);
      vz += *(const f32x4*)(rp + 16 + ej0);
      vn += *(const f32x4*)(rp + 32 + ej0);
    }
    unsigned short grs[4] = {(unsigned short)gr.x, (unsigned short)(gr.x >> 16),
                             (unsigned short)gr.y, (unsigned short)(gr.y >> 16)};
    unsigned short gzs[4] = {(unsigned short)gz.x, (unsigned short)(gz.x >> 16),
                             (unsigned short)gz.y, (unsigned short)(gz.y >> 16)};
    unsigned short gns[4] = {(unsigned short)gn.x, (unsigned short)(gn.x >> 16),
                             (unsigned short)gn.y, (unsigned short)(gn.y >> 16)};
    u64 ho = 0;
#pragma unroll
    for (int i = 0; i < 4; ++i) {
      float hr = vr[i] + (&bhr4.x)[i];
      float hz = vz[i] + (&bhz4.x)[i];
      float hn = vn[i] + (&bhn4.x)[i];
      float xr = b2f(grs[i]), xz = b2f(gzs[i]), xn = b2f(gns[i]);
      float rg = 1.f / (1.f + __expf(-(xr + hr)));
      float zg = 1.f / (1.f + __expf(-(xz + hz)));
      float pre = xn + rg * hn;
      pre = fminf(fmaxf(pre, -15.f), 15.f);
      float e = __expf(-2.f * pre);
      float ng = (1.f - e) / (1.f + e);
      float hp = b2f((unsigned short)(hprev >> (16 * i)));
      float hv = (1.f - zg) * ng + zg * hp;
      ho |= (u64)f2b(hv) << (16 * i);
    }
    // h output: MALL-visible store (consumers' caches hold no copy of this line)
    __hip_atomic_store(hnq + ((size_t)eb * Hh + ecol) / 4, ho,
                       __ATOMIC_RELAXED, __HIP_MEMORY_SCOPE_AGENT);
    hsave = ho;

    asm volatile("s_waitcnt vmcnt(0)" ::: "memory");  // h stores acked at MALL
    __syncthreads();  // all waves drained; also protects red[] reuse
    if (tid == 0)
      __hip_atomic_store(notify + (mg << 6) + gidx, (unsigned)(t + 1),
                         __ATOMIC_RELAXED, __HIP_MEMORY_SCOPE_AGENT);
    // history write AFTER notify -- off the critical path
    *(u64*)(hsc + (size_t)(eb * TC + tl) * Hh + ecol) = ho;
  }
}

// ---------------- logits GEMM (per chunk, M=8192) ----------------
__global__ __launch_bounds__(256) void k_logits(const unsigned short* __restrict__ hsc,
                                                const unsigned short* __restrict__ Wo,
                                                const float* __restrict__ bout,
                                                float* __restrict__ out, int t0) {
  int blk = blockIdx.x;
  int l = threadIdx.x & 63, w = threadIdx.x >> 6;
  int lr = l & 15, lk = (l >> 4) * 8;
  int r0 = blk * 64 + 16 * w;
  f32x4 acc[8] = {};
  for (int kk = 0; kk < 32; ++kk) {
    int k = kk * 32 + lk;
    bf16x8 a = *(const bf16x8*)(hsc + (size_t)(r0 + lr) * Hh + k);
#pragma unroll
    for (int nf = 0; nf < 8; ++nf) {
      bf16x8 b = *(const bf16x8*)(Wo + (size_t)(16 * nf + lr) * Hh + k);
      acc[nf] = __builtin_amdgcn_mfma_f32_16x16x32_bf16(a, b, acc[nf], 0, 0, 0);
    }
  }
  int ri = (l >> 4) * 4;
  for (int nf = 0; nf < 8; ++nf) {
    int c = 16 * nf + lr;
    float bo = bout[c];
#pragma unroll
    for (int i = 0; i < 4; ++i) {
      int m = r0 + ri + i;
      int grow = (m >> 5) * Tt + t0 + (m & 31);
      out[(size_t)grow * Cc + c] = acc[nf][i] + bo;
    }
  }
}

// ---------------- launch ----------------
extern "C" void kernel_launch(void* const* d_in, const int* in_sizes, int n_in,
                              void* d_out, int out_size, void* d_ws, size_t ws_size,
                              hipStream_t stream) {
  const float* gru = (const float*)d_in[0];
  const float* ts  = (const float*)d_in[1];
  const float* Wih = (const float*)d_in[2];
  const float* bih = (const float*)d_in[3];
  const float* Whh = (const float*)d_in[4];
  const float* bhh = (const float*)d_in[5];
  const float* Wou = (const float*)d_in[6];
  const float* bou = (const float*)d_in[7];

  char* ws = (char*)d_ws;
  size_t off = 0;
  auto alloc = [&](size_t bytes) -> void* {
    void* p = ws + off;
    off += (bytes + 255) & ~(size_t)255;
    return p;
  };
  unsigned short* Wa    = (unsigned short*)alloc((size_t)G3 * Dd * 2);
  unsigned short* WcT   = (unsigned short*)alloc((size_t)Cc * G3 * 2);
  unsigned short* Whb   = (unsigned short*)alloc((size_t)G3 * Hh * 2);
  unsigned short* Wob   = (unsigned short*)alloc((size_t)Cc * Hh * 2);
  int*            pid   = (int*)alloc((size_t)Bb * Tt * 4);
  unsigned short* hring = (unsigned short*)alloc((size_t)SLOTS * Bb * Hh * 2);  // 16.9MB
  unsigned int*   nfy   = (unsigned int*)alloc((size_t)4 * 64 * 4);
  unsigned short* Xc    = (unsigned short*)alloc((size_t)Bb * TC * Dd * 2);
  unsigned short* gx    = (unsigned short*)alloc((size_t)Bb * TC * G3 * 2);
  unsigned short* hsc   = (unsigned short*)alloc((size_t)Bb * TC * Hh * 2);
  if (ws_size < off) return;

  k_cvt<<<(G3 * Hh) / 2048, 256, 0, stream>>>(Whh, Whb, G3 * Hh);
  k_cvt<<<(Cc * Hh) / 2048, 256, 0, stream>>>(Wou, Wob, Cc * Hh);
  k_cvt_wa<<<(G3 * 64) / 256, 256, 0, stream>>>(Wih, Wa);
  k_cvt_wct<<<dim3(G3 / 256, Cc), 256, 0, stream>>>(Wih, WcT);
  k_pid<<<(Bb * Tt) / 256, 256, 0, stream>>>(ts, pid);
  hipMemsetAsync(hring, 0, (size_t)Bb * Hh * 2, stream);  // slot 0 = h(0) = 0
  hipMemsetAsync(nfy, 0, (size_t)4 * 64 * 4, stream);

  for (int c = 0; c < NC; ++c) {
    int t0 = c * TC;
    k_cvtx<<<(Bb * TC * Dd) / 2048, 256, 0, stream>>>(gru, Xc, t0);
    k_gates<<<dim3((Bb * TC) / 128, G3 / 128), 256, 0, stream>>>(Xc, Wa, WcT, bih, pid, gx, t0);
    k_scan<<<dim3(256), dim3(256), 0, stream>>>(Whb, bhh, gx, hring, hsc, nfy, t0);
    k_logits<<<(Bb * TC) / 64, 256, 0, stream>>>(hsc, Wob, bou, (float*)d_out, t0);
  }
}